// Round 2
// baseline (1061.458 us; speedup 1.0000x reference)
//
#include <hip/hip_runtime.h>
#include <hip/hip_bf16.h>
#include <hip/hip_fp16.h>

#define HID 1024
#define QCOLS 512

typedef _Float16 f16x8 __attribute__((ext_vector_type(8)));
typedef float f32x4 __attribute__((ext_vector_type(4)));

// ---- K0: transpose+convert+split: src[K][N] f32 -> hi/lo [N][K] f16 (scaled) --
__global__ void tconv_split(const float* __restrict__ src, __half* __restrict__ hi,
                            __half* __restrict__ lo, int K, int N, float scale) {
  __shared__ float tile[32][33];
  int n0 = blockIdx.x * 32, k0 = blockIdx.y * 32;
  int tx = threadIdx.x, ty = threadIdx.y;
  for (int i = ty; i < 32; i += 8)
    tile[i][tx] = src[(size_t)(k0 + i) * N + n0 + tx];
  __syncthreads();
  for (int i = ty; i < 32; i += 8) {
    float v = tile[tx][i] * scale;
    __half h = __float2half(v);
    size_t o = (size_t)(n0 + i) * K + k0 + tx;
    hi[o] = h;
    lo[o] = __float2half(v - __half2float(h));
  }
}

// ---- K1: h1 = relu(yA @ w1 + b1) in fp32, split to f16 hi/lo (x64) -----------
__global__ __launch_bounds__(256)
void h1_split(const float* __restrict__ y, const float* __restrict__ w1,
              const float* __restrict__ b1, __half* __restrict__ hi,
              __half* __restrict__ lo, int row0, int nrows) {
  int idx = blockIdx.x * 256 + threadIdx.x;
  if (idx >= nrows * HID) return;
  int r = idx >> 10, c = idx & (HID - 1);
  const float* yr = y + (size_t)(row0 + r) * 17;
  float acc = b1[c];
#pragma unroll
  for (int k = 0; k < 8; ++k) acc = fmaf(yr[k], w1[k * HID + c], acc);
  float v = fmaxf(acc, 0.f) * 64.f;
  __half h = __float2half(v);
  size_t o = (size_t)r * HID + c;
  hi[o] = h;
  lo[o] = __float2half(v - __half2float(h));
}

// ---- split-f16 MFMA GEMM: C = (Ahi+Alo)x(Bhi+Blo)^T fp32-grade ---------------
// 128x128 tile, BK=32, 4 waves (2x2). ACT 0: relu -> split f16 (x64). ACT 1:
// softplus -> f32.  acc is scaled by 2^14 (A x64, B x256); unscale = 2^-14.
template <int ACT>
__global__ __launch_bounds__(256)
void gemm_split(const __half* __restrict__ Ahi, const __half* __restrict__ Alo,
                const __half* __restrict__ Bhi, const __half* __restrict__ Blo,
                const float* __restrict__ bias, __half* __restrict__ Chi,
                __half* __restrict__ Clo, float* __restrict__ Cf,
                int M, int N, int K) {
  __shared__ __half lds[4][128 * 32];  // planes: Ahi, Alo, Bhi, Blo (8KB each)
  const int tid = threadIdx.x;
  const int wave = tid >> 6, lane = tid & 63;
  const int wr = (wave >> 1) * 64, wc = (wave & 1) * 64;
  const size_t row_blk = (size_t)blockIdx.y * 128;
  const size_t col_blk = (size_t)blockIdx.x * 128;

  f32x4 acc[4][4] = {};

  const int rr_l = lane >> 2;        // row within 16-row chunk
  const int kk_l = (lane & 3) * 8;   // k half-offset within 32-wide tile

  for (int kt = 0; kt < K; kt += 32) {
    __syncthreads();
#pragma unroll
    for (int j = 0; j < 2; ++j) {
      const int c = wave * 2 + j;                 // 1KB chunk: rows 16c..16c+15
      const int rr = c * 16 + rr_l;
      const size_t ga = (row_blk + rr) * (size_t)K + kt + kk_l;
      const size_t gb = (col_blk + rr) * (size_t)K + kt + kk_l;
      const int lo_off = c * 1024 + lane * 16;
      __builtin_amdgcn_global_load_lds((__attribute__((address_space(1))) void*)(Ahi + ga),
                                       (__attribute__((address_space(3))) void*)((char*)&lds[0][0] + lo_off), 16, 0, 0);
      __builtin_amdgcn_global_load_lds((__attribute__((address_space(1))) void*)(Alo + ga),
                                       (__attribute__((address_space(3))) void*)((char*)&lds[1][0] + lo_off), 16, 0, 0);
      __builtin_amdgcn_global_load_lds((__attribute__((address_space(1))) void*)(Bhi + gb),
                                       (__attribute__((address_space(3))) void*)((char*)&lds[2][0] + lo_off), 16, 0, 0);
      __builtin_amdgcn_global_load_lds((__attribute__((address_space(1))) void*)(Blo + gb),
                                       (__attribute__((address_space(3))) void*)((char*)&lds[3][0] + lo_off), 16, 0, 0);
    }
    __syncthreads();

    const int kb = (lane >> 4) * 16;  // byte offset of lane's 8 k-halves
    f16x8 ah[4], al[4], bh[4], bl[4];
#pragma unroll
    for (int m = 0; m < 4; ++m) {
      const int rb = (wr + m * 16 + (lane & 15)) * 64 + kb;
      ah[m] = *(const f16x8*)((const char*)&lds[0][0] + rb);
      al[m] = *(const f16x8*)((const char*)&lds[1][0] + rb);
    }
#pragma unroll
    for (int n = 0; n < 4; ++n) {
      const int rb = (wc + n * 16 + (lane & 15)) * 64 + kb;
      bh[n] = *(const f16x8*)((const char*)&lds[2][0] + rb);
      bl[n] = *(const f16x8*)((const char*)&lds[3][0] + rb);
    }
#pragma unroll
    for (int m = 0; m < 4; ++m)
#pragma unroll
      for (int n = 0; n < 4; ++n) {
        acc[m][n] = __builtin_amdgcn_mfma_f32_16x16x32_f16(ah[m], bh[n], acc[m][n], 0, 0, 0);
        acc[m][n] = __builtin_amdgcn_mfma_f32_16x16x32_f16(ah[m], bl[n], acc[m][n], 0, 0, 0);
        acc[m][n] = __builtin_amdgcn_mfma_f32_16x16x32_f16(al[m], bh[n], acc[m][n], 0, 0, 0);
      }
  }

  const float unscale = 1.f / 16384.f;
  // C/D frag map: col = lane&15, row = (lane>>4)*4 + j   [m89-verified]
#pragma unroll
  for (int m = 0; m < 4; ++m) {
    const size_t row_b = row_blk + wr + m * 16 + (lane >> 4) * 4;
#pragma unroll
    for (int n = 0; n < 4; ++n) {
      const size_t col = col_blk + wc + n * 16 + (lane & 15);
      const float bv = bias[col];
#pragma unroll
      for (int j = 0; j < 4; ++j) {
        float v = acc[m][n][j] * unscale + bv;
        const size_t o = (row_b + j) * (size_t)N + col;
        if constexpr (ACT == 0) {
          float r = fmaxf(v, 0.f) * 64.f;
          __half h = __float2half(r);
          Chi[o] = h;
          Clo[o] = __float2half(r - __half2float(h));
        } else {
          float sp = fmaxf(v, 0.f) + log1pf(expf(-fabsf(v)));  // stable softplus
          Cf[o] = sp + 1e-6f;
        }
      }
    }
  }
}

// ---- K4: per-row piecewise-linear inverse + jacobian (np-order-matched) ------
__global__ __launch_bounds__(256)
void epilogue_kernel(const float* __restrict__ y, const float* __restrict__ q,
                     float* __restrict__ out, int row0, int nrows) {
  const int wave = threadIdx.x >> 6, lane = threadIdx.x & 63;
  const int r = blockIdx.x * 4 + wave;
  if (r >= nrows) return;
  const float* yr = y + (size_t)(row0 + r) * 17;
  float* orow = out + (size_t)(row0 + r) * 17;
  const float* qr = q + (size_t)r * QCOLS;
  float prod_inv = 1.f;
#pragma unroll
  for (int t = 0; t < 8; ++t) {
    const float qv = qr[t * 64 + lane];
    float s = qv;  // inclusive prefix sum over 64 lanes
#pragma unroll
    for (int d = 1; d < 64; d <<= 1) {
      float u = __shfl_up(s, d);
      if (lane >= d) s += u;
    }
    const float total = __shfl(s, 63);
    const float sn = s / total;                  // normalized inclusive cumsum
    const float dnorm = total * 0.015625f;       // Qnorms / NBINS (exact mul)
    const float slope_l = qv / dnorm;            // normalized Q at this lane
    const float yb = yr[8 + t];
    const unsigned long long m = __ballot(sn < yb);
    int bin = (int)__popcll(m);
    bin = bin > 63 ? 63 : bin;
    const float off_g = __shfl(sn, bin > 0 ? bin - 1 : 0);
    const float off = (bin == 0) ? 0.f : off_g;  // paddedQsum[bin]
    const float sl = __shfl(slope_l, bin);
    const float xB = (yb - off) / sl + (float)bin * 0.015625f;
    if (lane == t) orow[8 + t] = xB;
    prod_inv *= (1.f / sl);
  }
  if (lane < 8) orow[lane] = yr[lane];
  if (lane == 8) orow[16] = yr[16] * prod_inv;
}

// ---- launch ------------------------------------------------------------------
extern "C" void kernel_launch(void* const* d_in, const int* in_sizes, int n_in,
                              void* d_out, int out_size, void* d_ws, size_t ws_size,
                              hipStream_t stream) {
  const float* y  = (const float*)d_in[0];
  const float* w1 = (const float*)d_in[1];
  const float* b1 = (const float*)d_in[2];
  const float* w2 = (const float*)d_in[3];
  const float* b2 = (const float*)d_in[4];
  const float* w3 = (const float*)d_in[5];
  const float* b3 = (const float*)d_in[6];
  float* out = (float*)d_out;
  const long Btot = in_sizes[0] / 17;

  char* ws = (char*)d_ws;
  __half* w2thi = (__half*)ws;                               // 2 MB [1024][1024]
  __half* w2tlo = (__half*)(ws + (2u << 20));                // 2 MB
  __half* w3thi = (__half*)(ws + (4u << 20));                // 1 MB [512][1024]
  __half* w3tlo = (__half*)(ws + (5u << 20));                // 1 MB
  const size_t fixed = (size_t)6 << 20;

  // per-row scratch: h1 hi/lo + h2 hi/lo = 4 x 2048 B; q (f32) reuses h1 region
  size_t avail = ws_size > fixed ? ws_size - fixed : 0;
  long maxrows = (long)(avail / 8192);
  long chunk = Btot < maxrows ? Btot : maxrows;
  chunk &= ~127L;
  if (chunk < 128) chunk = 128;

  __half* h1hi = (__half*)(ws + fixed);
  __half* h1lo = (__half*)(ws + fixed + (size_t)chunk * 2048);
  __half* h2hi = (__half*)(ws + fixed + (size_t)chunk * 4096);
  __half* h2lo = (__half*)(ws + fixed + (size_t)chunk * 6144);
  float* qbuf = (float*)h1hi;  // 2048 B/row, h1 dead when q is written

  dim3 tb(32, 8);
  tconv_split<<<dim3(HID / 32, HID / 32), tb, 0, stream>>>(w2, w2thi, w2tlo, HID, HID, 256.f);
  tconv_split<<<dim3(QCOLS / 32, HID / 32), tb, 0, stream>>>(w3, w3thi, w3tlo, HID, QCOLS, 256.f);

  for (long row0 = 0; row0 < Btot; row0 += chunk) {
    const int nr = (int)((Btot - row0 < chunk) ? (Btot - row0) : chunk);
    h1_split<<<nr * (HID / 256), 256, 0, stream>>>(y, w1, b1, h1hi, h1lo, (int)row0, nr);
    gemm_split<0><<<dim3(HID / 128, nr / 128), 256, 0, stream>>>(
        h1hi, h1lo, w2thi, w2tlo, b2, h2hi, h2lo, nullptr, nr, HID, HID);
    gemm_split<1><<<dim3(QCOLS / 128, nr / 128), 256, 0, stream>>>(
        h2hi, h2lo, w3thi, w3tlo, b3, nullptr, nullptr, qbuf, nr, QCOLS, HID);
    epilogue_kernel<<<(nr + 3) / 4, 256, 0, stream>>>(y, qbuf, out, (int)row0, nr);
  }
}